// Round 11
// baseline (267.286 us; speedup 1.0000x reference)
//
#include <hip/hip_runtime.h>
#include <hip/hip_cooperative_groups.h>

namespace cg = cooperative_groups;

// Volume rendering composite (cumprod along chunk-row axis, per-column).
// s[b,p] = density*delta >= 0; T = exp(-prefix(s)); monotone prefix =>
// exp(-S)==0 exactly in fp32 for S>110, so late contributions are exactly 0.
//
// Round-10 (resubmit; R9 bench was an infra failure): single cooperative
// kernel, 3 phases with grid.sync() between. R6's 3 dependent dispatches
// cost ~15us of launch/drain + wsA round-trip; manual fences (R7) were
// catastrophic, but grid.sync's cost should scale with dirty L2 data
// (only 0.5-2 MB here). Per-segment sums persist in LDS across phases
// (wsA eliminated). Fallback to the proven 3-kernel structure if the
// cooperative launch is unavailable.
//   P1: per-segment (8-row) sums -> LDS seg; superblock sums -> wsBS.
//   P2: 8-way-split prefix base from wsBS (fixed order) + intra-block seg
//       prefix; live waves composite (__expf); LDS reduce; partial -> wsB.
//   P3: blocks sb<8: fixed-order reduce of 128 partials -> d_out.

#define P 128
#define FARD 1.0e10f
#define SKIP_S 110.0f
#define SB 8           // segments (waves) per block
#define LROWS 8        // rows per segment; superblock = 64 rows

__device__ __forceinline__ void seg_phase(
    const float2* __restrict__ d2, const float2* __restrict__ z2,
    long long row0, int t, float& sx, float& sy)
{
    sx = 0.f; sy = 0.f;
    #pragma unroll
    for (int r = 0; r < LROWS; ++r) {
        const long long h = (row0 + r) * (P / 2) + t;
        float2 d = d2[h];
        float2 z = z2[h];
        float zn = __shfl_down(z.x, 1);
        sx += d.x * (z.y - z.x);
        sy += d.y * ((t == 63) ? FARD : (zn - z.y));
    }
}

__global__ __launch_bounds__(512, 8) void fused_kernel(
    const float* __restrict__ density,
    const float* __restrict__ feature,
    const float* __restrict__ depth,
    float* __restrict__ wsBS,   // [c][sb][P] superblock sums
    float* __restrict__ wsB,    // [c][sb][512] partials
    float* __restrict__ out,
    int nsb, int chunk, int n_chunks)
{
    cg::grid_group gg = cg::this_grid();
    __shared__ float2 seg2[SB][64];   // per-segment sums, persists P1->P2
    __shared__ float2 part2[8][64];
    __shared__ float red[SB][512];
    const int tid = threadIdx.x;
    const int w = tid >> 6, t = tid & 63;
    const int sb = blockIdx.x, c = blockIdx.y;
    const int g = sb * SB + w;
    const long long row0 = (long long)c * chunk + (long long)g * LROWS;
    const float2* __restrict__ d2 = (const float2*)density;
    const float2* __restrict__ z2 = (const float2*)depth;

    // ---- Phase 1: per-segment sums + superblock sums ----
    float sx, sy;
    seg_phase(d2, z2, row0, t, sx, sy);
    float2 o; o.x = sx; o.y = sy;
    seg2[w][t] = o;
    __syncthreads();
    if (w == 0) {
        float bx = 0.f, by = 0.f;
        #pragma unroll
        for (int k = 0; k < SB; ++k) { bx += seg2[k][t].x; by += seg2[k][t].y; }
        float2 b; b.x = bx; b.y = by;
        ((float2*)wsBS)[((long long)c * nsb + sb) * (P / 2) + t] = b;
    }
    gg.sync();

    // ---- Phase 2: prefix base (8-way split, fixed order) + composite ----
    {
        const int j = tid >> 6;                   // 0..7
        const float2* bs2 = (const float2*)wsBS;
        float bx = 0.f, by = 0.f;
        for (int sbp = j; sbp < sb; sbp += 8) {
            float2 v = bs2[((long long)c * nsb + sbp) * (P / 2) + t];
            bx += v.x; by += v.y;
        }
        float2 pr; pr.x = bx; pr.y = by;
        part2[j][t] = pr;
    }
    __syncthreads();

    float Sx = 0.f, Sy = 0.f;
    #pragma unroll
    for (int k = 0; k < 8; ++k) { Sx += part2[k][t].x; Sy += part2[k][t].y; }
    for (int k = 0; k < w; ++k) { Sx += seg2[k][t].x; Sy += seg2[k][t].y; }

    float fa0 = 0.f, fa1 = 0.f, fa2 = 0.f;
    float fb0 = 0.f, fb1 = 0.f, fb2 = 0.f;
    float da = 0.f, db = 0.f;

    const bool dead = __all((Sx > SKIP_S) && (Sy > SKIP_S));
    if (!dead) {
        const float2* __restrict__ f2 = (const float2*)feature;
        float tx = __expf(-Sx), ty = __expf(-Sy);
        #pragma unroll
        for (int r = 0; r < LROWS; ++r) {
            const long long hh = (row0 + r) * (P / 2) + t;
            float2 d = d2[hh];
            float2 z = z2[hh];
            float zn = __shfl_down(z.x, 1);
            float s1 = d.x * (z.y - z.x);
            float s2 = d.y * ((t == 63) ? FARD : (zn - z.y));
            float ex = __expf(-s1), ey = __expf(-s2);
            float tnx = tx * ex, tny = ty * ey;   // running cumprod, as ref
            float wx = tx - tnx;                  // T_i * (1 - temp_i)
            float wy = ty - tny;
            tx = tnx; ty = tny;
            const long long fi = 3 * hh;
            float2 f01 = f2[fi], f23 = f2[fi + 1], f45 = f2[fi + 2];
            fa0 += wx * f01.x; fa1 += wx * f01.y; fa2 += wx * f23.x;
            fb0 += wy * f23.y; fb1 += wy * f45.x; fb2 += wy * f45.y;
            da  += wx * z.x;   db  += wy * z.y;
        }
    }

    const int p0 = 2 * t;
    float* rw = red[w];
    rw[p0 * 3 + 0] = fa0; rw[p0 * 3 + 1] = fa1; rw[p0 * 3 + 2] = fa2;
    rw[p0 * 3 + 3] = fb0; rw[p0 * 3 + 4] = fb1; rw[p0 * 3 + 5] = fb2;
    rw[384 + p0] = da;    rw[384 + p0 + 1] = db;
    __syncthreads();

    {
        float s = 0.f;
        #pragma unroll
        for (int k = 0; k < SB; ++k) s += red[k][tid];
        wsB[((long long)c * nsb + sb) * 512 + tid] = s;
    }
    gg.sync();

    // ---- Phase 3: blocks sb<8 reduce partials -> out ----
    if (sb < 8) {
        const int q = sb;
        const int e = q * 64 + (tid & 63);
        const int k = tid >> 6;                   // 0..7
        float s = 0.f;
        for (int sbp = k; sbp < nsb; sbp += 8)
            s += wsB[((long long)c * nsb + sbp) * 512 + e];
        red[k][tid & 63] = s;
        __syncthreads();
        if (tid < 64) {
            float r = 0.f;
            #pragma unroll
            for (int k2 = 0; k2 < 8; ++k2) r += red[k2][tid];
            const int e2 = q * 64 + tid;
            if (e2 < 384) out[(long long)c * 384 + e2] = r;
            else out[(long long)n_chunks * 384 + (long long)c * P + (e2 - 384)] = r;
        }
    }
}

// ---------------- Fallback: proven round-6 3-kernel structure ----------------

__global__ __launch_bounds__(512) void seg_sum_kernel(
    const float* __restrict__ density,
    const float* __restrict__ depth,
    float* __restrict__ wsA, float* __restrict__ wsBS,
    int G, int nsb, int chunk)
{
    __shared__ float2 ls[SB][64];
    const int w = threadIdx.x >> 6, t = threadIdx.x & 63;
    const int sb = blockIdx.x, c = blockIdx.y;
    const int g = sb * SB + w;
    const long long row0 = (long long)c * chunk + (long long)g * LROWS;
    float sx, sy;
    seg_phase((const float2*)density, (const float2*)depth, row0, t, sx, sy);
    float2 o; o.x = sx; o.y = sy;
    ((float2*)wsA)[((long long)c * G + g) * (P / 2) + t] = o;
    ls[w][t] = o;
    __syncthreads();
    if (w == 0) {
        float bx = 0.f, by = 0.f;
        #pragma unroll
        for (int k = 0; k < SB; ++k) { bx += ls[k][t].x; by += ls[k][t].y; }
        float2 b; b.x = bx; b.y = by;
        ((float2*)wsBS)[((long long)c * nsb + sb) * (P / 2) + t] = b;
    }
}

__global__ __launch_bounds__(512) void composite_kernel(
    const float* __restrict__ density,
    const float* __restrict__ feature,
    const float* __restrict__ depth,
    const float* __restrict__ wsA,
    const float* __restrict__ wsBS,
    float* __restrict__ wsB,
    int G, int nsb, int chunk)
{
    __shared__ float part[4][P];
    __shared__ float base[P];
    __shared__ float seg[SB][P];
    __shared__ float red[SB][512];
    const int tid = threadIdx.x;
    const int w = tid >> 6, t = tid & 63;
    const int sb = blockIdx.x, c = blockIdx.y;
    {
        const int p = tid & (P - 1), j = tid >> 7;
        float s = 0.f;
        for (int sbp = j; sbp < sb; sbp += 4)
            s += wsBS[((long long)c * nsb + sbp) * P + p];
        part[j][p] = s;
    }
    {
        int idx = tid;
        int w2 = idx >> 7, p2 = idx & (P - 1);
        seg[w2][p2] = wsA[((long long)c * G + sb * SB + w2) * P + p2];
        idx += 512; w2 = idx >> 7; p2 = idx & (P - 1);
        seg[w2][p2] = wsA[((long long)c * G + sb * SB + w2) * P + p2];
    }
    __syncthreads();
    if (tid < P)
        base[tid] = (part[0][tid] + part[1][tid]) + (part[2][tid] + part[3][tid]);
    __syncthreads();
    const int p0 = 2 * t;
    float Sx = base[p0], Sy = base[p0 + 1];
    for (int k = 0; k < w; ++k) { Sx += seg[k][p0]; Sy += seg[k][p0 + 1]; }
    float fa0 = 0.f, fa1 = 0.f, fa2 = 0.f;
    float fb0 = 0.f, fb1 = 0.f, fb2 = 0.f;
    float da = 0.f, db = 0.f;
    const bool dead = __all((Sx > SKIP_S) && (Sy > SKIP_S));
    if (!dead) {
        const int g = sb * SB + w;
        const long long row0 = (long long)c * chunk + (long long)g * LROWS;
        const float2* __restrict__ d2 = (const float2*)density;
        const float2* __restrict__ z2 = (const float2*)depth;
        const float2* __restrict__ f2 = (const float2*)feature;
        float tx = __expf(-Sx), ty = __expf(-Sy);
        #pragma unroll
        for (int r = 0; r < LROWS; ++r) {
            const long long hh = (row0 + r) * (P / 2) + t;
            float2 d = d2[hh];
            float2 z = z2[hh];
            float zn = __shfl_down(z.x, 1);
            float s1 = d.x * (z.y - z.x);
            float s2 = d.y * ((t == 63) ? FARD : (zn - z.y));
            float ex = __expf(-s1), ey = __expf(-s2);
            float tnx = tx * ex, tny = ty * ey;
            float wx = tx - tnx, wy = ty - tny;
            tx = tnx; ty = tny;
            const long long fi = 3 * hh;
            float2 f01 = f2[fi], f23 = f2[fi + 1], f45 = f2[fi + 2];
            fa0 += wx * f01.x; fa1 += wx * f01.y; fa2 += wx * f23.x;
            fb0 += wy * f23.y; fb1 += wy * f45.x; fb2 += wy * f45.y;
            da  += wx * z.x;   db  += wy * z.y;
        }
    }
    float* rw = red[w];
    rw[p0 * 3 + 0] = fa0; rw[p0 * 3 + 1] = fa1; rw[p0 * 3 + 2] = fa2;
    rw[p0 * 3 + 3] = fb0; rw[p0 * 3 + 4] = fb1; rw[p0 * 3 + 5] = fb2;
    rw[384 + p0] = da;    rw[384 + p0 + 1] = db;
    __syncthreads();
    float s = 0.f;
    #pragma unroll
    for (int k = 0; k < SB; ++k) s += red[k][tid];
    wsB[((long long)c * nsb + sb) * 512 + tid] = s;
}

__global__ __launch_bounds__(64) void reduce_kernel(
    const float* __restrict__ wsB, float* __restrict__ out,
    int nsb, int n_chunks)
{
    const int b = blockIdx.x;
    const int c = b >> 3, q = b & 7;
    const int e = q * 64 + threadIdx.x;
    float s = 0.f;
    #pragma unroll 4
    for (int sb = 0; sb < nsb; ++sb)
        s += wsB[((long long)c * nsb + sb) * 512 + e];
    if (e < 384) out[(long long)c * 384 + e] = s;
    else out[(long long)n_chunks * 384 + (long long)c * P + (e - 384)] = s;
}

extern "C" void kernel_launch(void* const* d_in, const int* in_sizes, int n_in,
                              void* d_out, int out_size, void* d_ws, size_t ws_size,
                              hipStream_t stream)
{
    const float* density = (const float*)d_in[0];
    const float* feature = (const float*)d_in[1];
    const float* depth   = (const float*)d_in[2];
    float* out = (float*)d_out;

    const int B = in_sizes[0] / P;        // 65536
    int chunk = 8192;                     // matches setup_inputs() chunk_size
    int n_chunks = B / chunk;             // 8
    int nsb = chunk / (SB * LROWS);       // 128 superblocks per chunk
    const int G = nsb * SB;               // 1024 segments per chunk

    float* wsBS = (float*)d_ws;                          // 0.5 MB
    float* wsB  = wsBS + (size_t)n_chunks * nsb * P;     // 2 MB
    float* wsA  = wsB + (size_t)n_chunks * nsb * 512;    // 4 MB (fallback)

    dim3 grid(nsb, n_chunks), block(512);
    void* args[] = {(void*)&density, (void*)&feature, (void*)&depth,
                    (void*)&wsBS, (void*)&wsB, (void*)&out,
                    (void*)&nsb, (void*)&chunk, (void*)&n_chunks};
    hipError_t err = hipLaunchCooperativeKernel(
        (const void*)fused_kernel, grid, block, args, 0, stream);
    if (err != hipSuccess) {
        // Fallback: proven 3-kernel structure (R6, 39.8us).
        seg_sum_kernel<<<grid, 512, 0, stream>>>(density, depth, wsA, wsBS,
                                                 G, nsb, chunk);
        composite_kernel<<<grid, 512, 0, stream>>>(density, feature, depth,
                                                   wsA, wsBS, wsB, G, nsb, chunk);
        reduce_kernel<<<n_chunks * 8, 64, 0, stream>>>(wsB, out, nsb, n_chunks);
    }
}

// Round 12
// 40.603 us; speedup vs baseline: 6.5830x; 6.5830x over previous
//
#include <hip/hip_runtime.h>

// Volume rendering composite (cumprod along chunk-row axis, per-column).
// s[b,p] = density*delta >= 0; T = exp(-prefix(s)); monotone prefix =>
// exp(-S)==0 exactly in fp32 for S>110, so late contributions are exactly 0.
//
// PROVEN structure: 3 small dependent dispatches. Grid-wide sync is ruled
// out on this chip: manual fence+counter (R7) = 248us, cooperative
// grid.sync (R11) = 267us — both ~100+us of cross-XCD wait vs ~10us of
// dispatch overhead for the 3-kernel chain. No hipMemsetAsync (57us fill).
//
// R12 change vs R6 (39.8us): composite grid TRANSPOSED to (chunk, sb).
// Live superblocks are sb<~37 for every chunk; with (sb, chunk) ordering
// the ~300 live blocks all land on ~74 CUs (index mod 256 collisions),
// leaving 70% of the chip idle during the cold 29MB feature stream.
// Transposing makes live blocks contiguous in dispatch index -> spread
// across all 256 CUs under breadth-first dispatch.
//   K1 seg_sum:   per-segment (8-row) column sums -> wsA, superblock
//                 (64-row) sums -> wsBS.
//   K2 composite: prefix base from coalesced L2-resident superblock sums
//                 (fixed order) + intra-block segment prefix in LDS; live
//                 waves composite with __expf; LDS tree-reduce; ONE plain
//                 512-float partial store. Dead blocks store zero partials.
//   K3 reduce:    fixed-order sum over 128 partials -> d_out.

#define P 128
#define FARD 1.0e10f
#define SKIP_S 110.0f
#define SB 8           // segments (waves) per block
#define LROWS 8        // rows per segment; superblock = 64 rows

__global__ __launch_bounds__(512) void seg_sum_kernel(
    const float* __restrict__ density,
    const float* __restrict__ depth,
    float* __restrict__ wsA,    // [c][g][P] per-segment sums
    float* __restrict__ wsBS,   // [c][sb][P] superblock sums
    int G, int nsb, int chunk)
{
    __shared__ float2 ls[SB][64];
    const int w = threadIdx.x >> 6;               // segment within block
    const int t = threadIdx.x & 63;               // lane -> cols 2t, 2t+1
    const int sb = blockIdx.x, c = blockIdx.y;
    const int g = sb * SB + w;
    const long long row0 = (long long)c * chunk + (long long)g * LROWS;
    const float2* __restrict__ d2 = (const float2*)density;
    const float2* __restrict__ z2 = (const float2*)depth;
    float sx = 0.f, sy = 0.f;
    #pragma unroll
    for (int r = 0; r < LROWS; ++r) {
        const long long h = (row0 + r) * (P / 2) + t;
        float2 d = d2[h];
        float2 z = z2[h];
        float zn = __shfl_down(z.x, 1);           // depth[b, 2t+2]
        sx += d.x * (z.y - z.x);
        sy += d.y * ((t == 63) ? FARD : (zn - z.y));
    }
    float2 o; o.x = sx; o.y = sy;
    ((float2*)wsA)[((long long)c * G + g) * (P / 2) + t] = o;
    ls[w][t] = o;
    __syncthreads();
    if (w == 0) {
        float bx = 0.f, by = 0.f;
        #pragma unroll
        for (int k = 0; k < SB; ++k) { bx += ls[k][t].x; by += ls[k][t].y; }
        float2 b; b.x = bx; b.y = by;
        ((float2*)wsBS)[((long long)c * nsb + sb) * (P / 2) + t] = b;
    }
}

__global__ __launch_bounds__(512) void composite_kernel(
    const float* __restrict__ density,
    const float* __restrict__ feature,
    const float* __restrict__ depth,
    const float* __restrict__ wsA,
    const float* __restrict__ wsBS,
    float* __restrict__ wsB,    // [c][sb][512] partials
    int G, int nsb, int chunk)
{
    __shared__ float part[4][P];
    __shared__ float base[P];
    __shared__ float seg[SB][P];
    __shared__ float red[SB][512];
    const int tid = threadIdx.x;
    const int w = tid >> 6, t = tid & 63;
    const int c = blockIdx.x, sb = blockIdx.y;    // TRANSPOSED grid (R12)

    // base[p] = sum_{sb'<sb} wsBS[c][sb'][p], fixed-order 4-way split.
    {
        const int p = tid & (P - 1), j = tid >> 7;        // j = 0..3
        float s = 0.f;
        for (int sbp = j; sbp < sb; sbp += 4)
            s += wsBS[((long long)c * nsb + sbp) * P + p];
        part[j][p] = s;
    }
    // Own 8 segment sums -> LDS (2 coalesced loads per thread).
    {
        int idx = tid;
        int w2 = idx >> 7, p2 = idx & (P - 1);
        seg[w2][p2] = wsA[((long long)c * G + sb * SB + w2) * P + p2];
        idx += 512; w2 = idx >> 7; p2 = idx & (P - 1);
        seg[w2][p2] = wsA[((long long)c * G + sb * SB + w2) * P + p2];
    }
    __syncthreads();
    if (tid < P)
        base[tid] = (part[0][tid] + part[1][tid]) + (part[2][tid] + part[3][tid]);
    __syncthreads();

    const int p0 = 2 * t;
    float Sx = base[p0], Sy = base[p0 + 1];
    for (int k = 0; k < w; ++k) { Sx += seg[k][p0]; Sy += seg[k][p0 + 1]; }

    float fa0 = 0.f, fa1 = 0.f, fa2 = 0.f;
    float fb0 = 0.f, fb1 = 0.f, fb2 = 0.f;
    float da = 0.f, db = 0.f;

    const bool dead = __all((Sx > SKIP_S) && (Sy > SKIP_S));
    if (!dead) {
        const int g = sb * SB + w;
        const long long row0 = (long long)c * chunk + (long long)g * LROWS;
        const float2* __restrict__ d2 = (const float2*)density;
        const float2* __restrict__ z2 = (const float2*)depth;
        const float2* __restrict__ f2 = (const float2*)feature;
        float tx = __expf(-Sx), ty = __expf(-Sy);  // T at segment start
        #pragma unroll
        for (int r = 0; r < LROWS; ++r) {
            const long long hh = (row0 + r) * (P / 2) + t;
            float2 d = d2[hh];
            float2 z = z2[hh];
            float zn = __shfl_down(z.x, 1);
            float sx = d.x * (z.y - z.x);
            float sy = d.y * ((t == 63) ? FARD : (zn - z.y));
            float ex = __expf(-sx), ey = __expf(-sy);
            float tnx = tx * ex, tny = ty * ey;   // running cumprod, as ref
            float wx = tx - tnx;                  // T_i * (1 - temp_i)
            float wy = ty - tny;
            tx = tnx; ty = tny;
            const long long fi = 3 * hh;
            float2 f01 = f2[fi], f23 = f2[fi + 1], f45 = f2[fi + 2];
            fa0 += wx * f01.x; fa1 += wx * f01.y; fa2 += wx * f23.x;
            fb0 += wy * f23.y; fb1 += wy * f45.x; fb2 += wy * f45.y;
            da  += wx * z.x;   db  += wy * z.y;
        }
    }

    // Per-wave partials -> LDS. Layout per wave: [p*3+comp | 384+p].
    float* rw = red[w];
    rw[p0 * 3 + 0] = fa0; rw[p0 * 3 + 1] = fa1; rw[p0 * 3 + 2] = fa2;
    rw[p0 * 3 + 3] = fb0; rw[p0 * 3 + 4] = fb1; rw[p0 * 3 + 5] = fb2;
    rw[384 + p0] = da;    rw[384 + p0 + 1] = db;
    __syncthreads();

    float s = 0.f;
    #pragma unroll
    for (int k = 0; k < SB; ++k) s += red[k][tid];
    wsB[((long long)c * nsb + sb) * 512 + tid] = s;
}

__global__ __launch_bounds__(64) void reduce_kernel(
    const float* __restrict__ wsB,
    float* __restrict__ out,
    int nsb, int n_chunks)
{
    const int b = blockIdx.x;                     // 8 blocks per chunk
    const int c = b >> 3, q = b & 7;
    const int e = q * 64 + threadIdx.x;           // 0..511
    float s = 0.f;
    #pragma unroll 4
    for (int sb = 0; sb < nsb; ++sb)
        s += wsB[((long long)c * nsb + sb) * 512 + e];
    if (e < 384) out[(long long)c * 384 + e] = s;                    // feat
    else out[(long long)n_chunks * 384 + (long long)c * P + (e - 384)] = s;
}

extern "C" void kernel_launch(void* const* d_in, const int* in_sizes, int n_in,
                              void* d_out, int out_size, void* d_ws, size_t ws_size,
                              hipStream_t stream)
{
    const float* density = (const float*)d_in[0];
    const float* feature = (const float*)d_in[1];
    const float* depth   = (const float*)d_in[2];
    float* out = (float*)d_out;

    const int B = in_sizes[0] / P;        // 65536
    const int chunk = 8192;               // matches setup_inputs() chunk_size
    const int n_chunks = B / chunk;       // 8
    const int nsb = chunk / (SB * LROWS); // 128 superblocks per chunk
    const int G = nsb * SB;               // 1024 segments per chunk

    float* wsA  = (float*)d_ws;                          // 4 MB
    float* wsBS = wsA + (size_t)n_chunks * G * P;        // 0.5 MB
    float* wsB  = wsBS + (size_t)n_chunks * nsb * P;     // 2 MB

    dim3 grid1(nsb, n_chunks);
    seg_sum_kernel<<<grid1, 512, 0, stream>>>(density, depth, wsA, wsBS,
                                              G, nsb, chunk);
    dim3 grid2(n_chunks, nsb);            // transposed: live blocks contiguous
    composite_kernel<<<grid2, 512, 0, stream>>>(density, feature, depth,
                                                wsA, wsBS, wsB, G, nsb, chunk);
    reduce_kernel<<<n_chunks * 8, 64, 0, stream>>>(wsB, out, nsb, n_chunks);
}

// Round 13
// 33.930 us; speedup vs baseline: 7.8775x; 1.1966x over previous
//
#include <hip/hip_runtime.h>

// Volume rendering composite (cumprod along chunk-row axis, per-column).
// s[b,p] = density*delta >= 0; T = exp(-prefix(s)); monotone prefix =>
// exp(-S)==0 exactly in fp32 for S>110, so late contributions are exactly 0.
//
// PROVEN: 3 small dependent dispatches. Grid-wide sync ruled out (R7 fence
// 248us, R11 cooperative 267us). No hipMemsetAsync (57us fill).
//
// R13: SPECULATIVE HALF-SCAN. All s>=0, so a prefix over a subset of rows
// is a lower bound on S. K1 scans only rows < chunk/2 (32 MB not 64 MB).
// K2, for superblocks in the upper half, uses S_lb = prefix@(chunk/2):
// if all columns have S_lb > 110 the block is EXACTLY dead. For this data
// prefix@4096 ~ 190 >> 110; a per-wave fallback (scan the missing rows
// directly) keeps the kernel exact for any input but never triggers here.
// Dead blocks also skip the wsA read entirely (block-level dead check
// from the L2-resident superblock sums before touching segment sums).
//   K1 seg_sum:   rows < chunk/2 only; per-segment sums -> wsA,
//                 superblock (64-row) sums -> wsBS.
//   K2 composite: base from coalesced superblock sums (fixed order);
//                 block-dead -> zero partial store, exit. Else intra-block
//                 segment prefix; live waves composite (__expf); LDS
//                 reduce; ONE 512-float partial store.
//   K3 reduce:    fixed-order sum over partials -> d_out.

#define P 128
#define FARD 1.0e10f
#define SKIP_S 110.0f
#define SB 8           // segments (waves) per block
#define LROWS 8        // rows per segment; superblock = 64 rows

__global__ __launch_bounds__(512) void seg_sum_kernel(
    const float* __restrict__ density,
    const float* __restrict__ depth,
    float* __restrict__ wsA,    // [c][g<GH][P] per-segment sums (lower half)
    float* __restrict__ wsBS,   // [c][sb<nsbH][P] superblock sums
    int GH, int nsbH, int chunk)
{
    __shared__ float2 ls[SB][64];
    const int w = threadIdx.x >> 6;               // segment within block
    const int t = threadIdx.x & 63;               // lane -> cols 2t, 2t+1
    const int sb = blockIdx.x, c = blockIdx.y;
    const int g = sb * SB + w;
    const long long row0 = (long long)c * chunk + (long long)g * LROWS;
    const float2* __restrict__ d2 = (const float2*)density;
    const float2* __restrict__ z2 = (const float2*)depth;
    float sx = 0.f, sy = 0.f;
    #pragma unroll
    for (int r = 0; r < LROWS; ++r) {
        const long long h = (row0 + r) * (P / 2) + t;
        float2 d = d2[h];
        float2 z = z2[h];
        float zn = __shfl_down(z.x, 1);           // depth[b, 2t+2]
        sx += d.x * (z.y - z.x);
        sy += d.y * ((t == 63) ? FARD : (zn - z.y));
    }
    float2 o; o.x = sx; o.y = sy;
    ((float2*)wsA)[((long long)c * GH + g) * (P / 2) + t] = o;
    ls[w][t] = o;
    __syncthreads();
    if (w == 0) {
        float bx = 0.f, by = 0.f;
        #pragma unroll
        for (int k = 0; k < SB; ++k) { bx += ls[k][t].x; by += ls[k][t].y; }
        float2 b; b.x = bx; b.y = by;
        ((float2*)wsBS)[((long long)c * nsbH + sb) * (P / 2) + t] = b;
    }
}

__global__ __launch_bounds__(512) void composite_kernel(
    const float* __restrict__ density,
    const float* __restrict__ feature,
    const float* __restrict__ depth,
    const float* __restrict__ wsA,
    const float* __restrict__ wsBS,
    float* __restrict__ wsB,    // [c][sb][512] partials
    int GH, int nsbH, int nsb, int chunk)
{
    __shared__ float part[4][P];
    __shared__ float base[P];
    __shared__ float seg[SB][P];
    __shared__ float red[SB][512];
    __shared__ int alive;
    const int tid = threadIdx.x;
    const int w = tid >> 6, t = tid & 63;
    const int c = blockIdx.x, sb = blockIdx.y;    // transposed grid

    // base[p]: exact prefix at this superblock's start if sb < nsbH,
    // else lower bound = exact prefix at row nsbH*64 (all terms >= 0).
    {
        const int p = tid & (P - 1), j = tid >> 7;        // j = 0..3
        const int lim = (sb < nsbH) ? sb : nsbH;
        float s = 0.f;
        for (int sbp = j; sbp < lim; sbp += 4)
            s += wsBS[((long long)c * nsbH + sbp) * P + p];
        part[j][p] = s;
    }
    if (tid == 0) alive = 0;
    __syncthreads();
    if (tid < P) {
        float b = (part[0][tid] + part[1][tid]) + (part[2][tid] + part[3][tid]);
        base[tid] = b;
        if (b <= SKIP_S) alive = 1;               // benign same-value race
    }
    __syncthreads();

    if (!alive) {                                 // whole block exactly dead
        wsB[((long long)c * nsb + sb) * 512 + tid] = 0.f;
        return;
    }

    const float2* __restrict__ d2 = (const float2*)density;
    const float2* __restrict__ z2 = (const float2*)depth;
    const int p0 = 2 * t;
    float Sx, Sy;

    if (sb < nsbH) {
        // Own 8 segment sums -> LDS (2 coalesced loads per thread).
        int idx = tid;
        int w2 = idx >> 7, p2 = idx & (P - 1);
        seg[w2][p2] = wsA[((long long)c * GH + sb * SB + w2) * P + p2];
        idx += 512; w2 = idx >> 7; p2 = idx & (P - 1);
        seg[w2][p2] = wsA[((long long)c * GH + sb * SB + w2) * P + p2];
        __syncthreads();
        Sx = base[p0]; Sy = base[p0 + 1];
        for (int k = 0; k < w; ++k) { Sx += seg[k][p0]; Sy += seg[k][p0 + 1]; }
    } else {
        // Fallback (never taken for realistic data): exact base by scanning
        // the rows K1 skipped: [nsbH*SB*LROWS, this segment's row0).
        Sx = base[p0]; Sy = base[p0 + 1];
        const long long rowH = (long long)nsbH * SB * LROWS;
        const long long rowStart = (long long)sb * SB * LROWS + (long long)w * LROWS;
        const long long cb = (long long)c * chunk;
        for (long long r = rowH; r < rowStart; ++r) {
            const long long h = (cb + r) * (P / 2) + t;
            float2 d = d2[h];
            float2 z = z2[h];
            float zn = __shfl_down(z.x, 1);
            Sx += d.x * (z.y - z.x);
            Sy += d.y * ((t == 63) ? FARD : (zn - z.y));
        }
    }

    float fa0 = 0.f, fa1 = 0.f, fa2 = 0.f;
    float fb0 = 0.f, fb1 = 0.f, fb2 = 0.f;
    float da = 0.f, db = 0.f;

    const bool dead = __all((Sx > SKIP_S) && (Sy > SKIP_S));
    if (!dead) {
        const int g = sb * SB + w;
        const long long row0 = (long long)c * chunk + (long long)g * LROWS;
        const float2* __restrict__ f2 = (const float2*)feature;
        float tx = __expf(-Sx), ty = __expf(-Sy);  // T at segment start
        #pragma unroll
        for (int r = 0; r < LROWS; ++r) {
            const long long hh = (row0 + r) * (P / 2) + t;
            float2 d = d2[hh];
            float2 z = z2[hh];
            float zn = __shfl_down(z.x, 1);
            float sx = d.x * (z.y - z.x);
            float sy = d.y * ((t == 63) ? FARD : (zn - z.y));
            float ex = __expf(-sx), ey = __expf(-sy);
            float tnx = tx * ex, tny = ty * ey;   // running cumprod, as ref
            float wx = tx - tnx;                  // T_i * (1 - temp_i)
            float wy = ty - tny;
            tx = tnx; ty = tny;
            const long long fi = 3 * hh;
            float2 f01 = f2[fi], f23 = f2[fi + 1], f45 = f2[fi + 2];
            fa0 += wx * f01.x; fa1 += wx * f01.y; fa2 += wx * f23.x;
            fb0 += wy * f23.y; fb1 += wy * f45.x; fb2 += wy * f45.y;
            da  += wx * z.x;   db  += wy * z.y;
        }
    }

    // Per-wave partials -> LDS. Layout per wave: [p*3+comp | 384+p].
    float* rw = red[w];
    rw[p0 * 3 + 0] = fa0; rw[p0 * 3 + 1] = fa1; rw[p0 * 3 + 2] = fa2;
    rw[p0 * 3 + 3] = fb0; rw[p0 * 3 + 4] = fb1; rw[p0 * 3 + 5] = fb2;
    rw[384 + p0] = da;    rw[384 + p0 + 1] = db;
    __syncthreads();

    float s = 0.f;
    #pragma unroll
    for (int k = 0; k < SB; ++k) s += red[k][tid];
    wsB[((long long)c * nsb + sb) * 512 + tid] = s;
}

__global__ __launch_bounds__(64) void reduce_kernel(
    const float* __restrict__ wsB,
    float* __restrict__ out,
    int nsb, int n_chunks)
{
    const int b = blockIdx.x;                     // 8 blocks per chunk
    const int c = b >> 3, q = b & 7;
    const int e = q * 64 + threadIdx.x;           // 0..511
    float s = 0.f;
    #pragma unroll 4
    for (int sb = 0; sb < nsb; ++sb)
        s += wsB[((long long)c * nsb + sb) * 512 + e];
    if (e < 384) out[(long long)c * 384 + e] = s;                    // feat
    else out[(long long)n_chunks * 384 + (long long)c * P + (e - 384)] = s;
}

extern "C" void kernel_launch(void* const* d_in, const int* in_sizes, int n_in,
                              void* d_out, int out_size, void* d_ws, size_t ws_size,
                              hipStream_t stream)
{
    const float* density = (const float*)d_in[0];
    const float* feature = (const float*)d_in[1];
    const float* depth   = (const float*)d_in[2];
    float* out = (float*)d_out;

    const int B = in_sizes[0] / P;        // 65536
    const int chunk = 8192;               // matches setup_inputs() chunk_size
    const int n_chunks = B / chunk;       // 8
    const int nsb = chunk / (SB * LROWS); // 128 superblocks per chunk
    const int nsbH = nsb / 2;             // K1 scans only the lower half
    const int GH = nsbH * SB;             // 512 segments per chunk (half)

    float* wsA  = (float*)d_ws;                          // 2 MB
    float* wsBS = wsA + (size_t)n_chunks * GH * P;       // 0.25 MB
    float* wsB  = wsBS + (size_t)n_chunks * nsbH * P;    // 2 MB

    dim3 grid1(nsbH, n_chunks);
    seg_sum_kernel<<<grid1, 512, 0, stream>>>(density, depth, wsA, wsBS,
                                              GH, nsbH, chunk);
    dim3 grid2(n_chunks, nsb);            // transposed: live blocks contiguous
    composite_kernel<<<grid2, 512, 0, stream>>>(density, feature, depth,
                                                wsA, wsBS, wsB,
                                                GH, nsbH, nsb, chunk);
    reduce_kernel<<<n_chunks * 8, 64, 0, stream>>>(wsB, out, nsb, n_chunks);
}

// Round 15
// 32.041 us; speedup vs baseline: 8.3421x; 1.0590x over previous
//
#include <hip/hip_runtime.h>

// Volume rendering composite (cumprod along chunk-row axis, per-column).
// s[b,p] = density*delta >= 0; T = exp(-prefix(s)); monotone prefix =>
// exp(-S)==0 exactly in fp32 for S>110, so late contributions are exactly 0.
//
// PROVEN: 3 small dependent dispatches (grid-wide sync ruled out: R7 fence
// 248us, R11 cooperative 267us; no hipMemsetAsync: 57us fill).
// R13 proved bytes are the lever (half-scan: -6.7us, matched prediction).
//
// R14 (resubmit; bench was an infra failure): (a) scan limit 64->48
// superblocks (rows<3072, 24 MB): S@3072 has mean 142.8, sigma 3.3 ->
// 9.9 sigma above the 110 cutoff (min over 127 cols ~133.8); exact
// per-wave fallback covers adversarial inputs. (b) K2 at 1024 thr =
// 16 waves x 4-row segments (superblock stays 64 rows so prefix-rebuild
// cost is UNCHANGED — R9's mistake was shrinking the superblock too).
// Live waves/SIMD ~2.3 -> ~4.6; cumprod chain 8 -> 4. K1 emits exact
// 4-row quarter-segment sums (two per wave, same reads).

#define P 128
#define FARD 1.0e10f
#define SKIP_S 110.0f
#define SB 8           // waves per K1 block (8-row ranges); superblock = 64 rows
#define NSBH 48        // superblocks scanned by K1 (rows < 3072)
#define QSEG 16        // 4-row quarter-segments per superblock

__global__ __launch_bounds__(512) void seg_sum_kernel(
    const float* __restrict__ density,
    const float* __restrict__ depth,
    float* __restrict__ wsA,    // [c][sb<NSBH][QSEG][P] 4-row segment sums
    float* __restrict__ wsBS,   // [c][sb<NSBH][P] superblock sums
    int chunk)
{
    __shared__ float2 ls[SB][64];
    const int w = threadIdx.x >> 6;               // 8-row range within block
    const int t = threadIdx.x & 63;               // lane -> cols 2t, 2t+1
    const int sb = blockIdx.x, c = blockIdx.y;
    const long long row0 = (long long)c * chunk + ((long long)sb * SB + w) * 8;
    const float2* __restrict__ d2 = (const float2*)density;
    const float2* __restrict__ z2 = (const float2*)depth;
    float sx0 = 0.f, sy0 = 0.f, sx1 = 0.f, sy1 = 0.f;
    #pragma unroll
    for (int r = 0; r < 8; ++r) {
        const long long h = (row0 + r) * (P / 2) + t;
        float2 d = d2[h];
        float2 z = z2[h];
        float zn = __shfl_down(z.x, 1);           // depth[b, 2t+2]
        float ax = d.x * (z.y - z.x);
        float ay = d.y * ((t == 63) ? FARD : (zn - z.y));
        if (r < 4) { sx0 += ax; sy0 += ay; }
        else       { sx1 += ax; sy1 += ay; }
    }
    float2* wa2 = (float2*)wsA;
    const long long qb = (((long long)c * NSBH + sb) * QSEG + 2 * w) * 64 + t;
    float2 o0; o0.x = sx0; o0.y = sy0;
    float2 o1; o1.x = sx1; o1.y = sy1;
    wa2[qb] = o0;
    wa2[qb + 64] = o1;
    float2 oT; oT.x = sx0 + sx1; oT.y = sy0 + sy1;
    ls[w][t] = oT;
    __syncthreads();
    if (w == 0) {
        float bx = 0.f, by = 0.f;
        #pragma unroll
        for (int k = 0; k < SB; ++k) { bx += ls[k][t].x; by += ls[k][t].y; }
        float2 b; b.x = bx; b.y = by;
        ((float2*)wsBS)[((long long)c * NSBH + sb) * (P / 2) + t] = b;
    }
}

__global__ __launch_bounds__(1024) void composite_kernel(
    const float* __restrict__ density,
    const float* __restrict__ feature,
    const float* __restrict__ depth,
    const float* __restrict__ wsA,
    const float* __restrict__ wsBS,
    float* __restrict__ wsB,    // [c][sb][512] partials
    int nsb, int chunk)
{
    __shared__ float part[8][P];
    __shared__ float base[P];
    __shared__ float seg[QSEG][P];
    __shared__ float red[QSEG][512];
    __shared__ int alive;
    const int tid = threadIdx.x;
    const int w = tid >> 6, t = tid & 63;         // 16 waves; 4-row segments
    const int c = blockIdx.x, sb = blockIdx.y;    // transposed grid

    // base[p]: exact prefix at superblock start if sb < NSBH, else exact
    // prefix at row NSBH*64 (a lower bound for upper blocks; s >= 0).
    {
        const int p = tid & (P - 1), j = tid >> 7;        // j = 0..7
        const int lim = (sb < NSBH) ? sb : NSBH;
        float s = 0.f;
        for (int sbp = j; sbp < lim; sbp += 8)
            s += wsBS[((long long)c * NSBH + sbp) * P + p];
        part[j][p] = s;
    }
    if (tid == 0) alive = 0;
    __syncthreads();
    if (tid < P) {
        float b = ((part[0][tid] + part[1][tid]) + (part[2][tid] + part[3][tid]))
                + ((part[4][tid] + part[5][tid]) + (part[6][tid] + part[7][tid]));
        base[tid] = b;
        if (b <= SKIP_S) alive = 1;               // benign same-value race
    }
    __syncthreads();

    if (!alive) {                                 // whole block exactly dead
        if (tid < 512) wsB[((long long)c * nsb + sb) * 512 + tid] = 0.f;
        return;
    }

    const float2* __restrict__ d2 = (const float2*)density;
    const float2* __restrict__ z2 = (const float2*)depth;
    const int p0 = 2 * t;
    float Sx, Sy;

    if (sb < NSBH) {
        // 16 segment sums -> LDS (2 coalesced loads per thread).
        {
            int idx = tid;
            seg[idx >> 7][idx & (P - 1)] =
                wsA[(((long long)c * NSBH + sb) * QSEG + (idx >> 7)) * P + (idx & (P - 1))];
            idx = tid + 1024;
            seg[idx >> 7][idx & (P - 1)] =
                wsA[(((long long)c * NSBH + sb) * QSEG + (idx >> 7)) * P + (idx & (P - 1))];
        }
        __syncthreads();
        Sx = base[p0]; Sy = base[p0 + 1];
        for (int k = 0; k < w; ++k) { Sx += seg[k][p0]; Sy += seg[k][p0 + 1]; }
    } else {
        // Fallback (never taken for realistic data): exact base by scanning
        // rows K1 skipped: [NSBH*64, this segment's first row).
        Sx = base[p0]; Sy = base[p0 + 1];
        const long long cb = (long long)c * chunk;
        const long long rowH = (long long)NSBH * 64;
        const long long rowStart = (long long)sb * 64 + (long long)w * 4;
        for (long long r = rowH; r < rowStart; ++r) {
            const long long h = (cb + r) * (P / 2) + t;
            float2 d = d2[h];
            float2 z = z2[h];
            float zn = __shfl_down(z.x, 1);
            Sx += d.x * (z.y - z.x);
            Sy += d.y * ((t == 63) ? FARD : (zn - z.y));
        }
    }

    float fa0 = 0.f, fa1 = 0.f, fa2 = 0.f;
    float fb0 = 0.f, fb1 = 0.f, fb2 = 0.f;
    float da = 0.f, db = 0.f;

    const bool dead = __all((Sx > SKIP_S) && (Sy > SKIP_S));
    if (!dead) {
        const long long row0 = (long long)c * chunk + (long long)sb * 64 + (long long)w * 4;
        const float2* __restrict__ f2 = (const float2*)feature;
        float tx = __expf(-Sx), ty = __expf(-Sy);  // T at segment start
        #pragma unroll
        for (int r = 0; r < 4; ++r) {
            const long long hh = (row0 + r) * (P / 2) + t;
            float2 d = d2[hh];
            float2 z = z2[hh];
            float zn = __shfl_down(z.x, 1);
            float sx = d.x * (z.y - z.x);
            float sy = d.y * ((t == 63) ? FARD : (zn - z.y));
            float ex = __expf(-sx), ey = __expf(-sy);
            float tnx = tx * ex, tny = ty * ey;   // running cumprod, as ref
            float wx = tx - tnx;                  // T_i * (1 - temp_i)
            float wy = ty - tny;
            tx = tnx; ty = tny;
            const long long fi = 3 * hh;
            float2 f01 = f2[fi], f23 = f2[fi + 1], f45 = f2[fi + 2];
            fa0 += wx * f01.x; fa1 += wx * f01.y; fa2 += wx * f23.x;
            fb0 += wy * f23.y; fb1 += wy * f45.x; fb2 += wy * f45.y;
            da  += wx * z.x;   db  += wy * z.y;
        }
    }

    // Per-wave partials -> LDS. Layout per wave: [p*3+comp | 384+p].
    float* rw = red[w];
    rw[p0 * 3 + 0] = fa0; rw[p0 * 3 + 1] = fa1; rw[p0 * 3 + 2] = fa2;
    rw[p0 * 3 + 3] = fb0; rw[p0 * 3 + 4] = fb1; rw[p0 * 3 + 5] = fb2;
    rw[384 + p0] = da;    rw[384 + p0 + 1] = db;
    __syncthreads();

    if (tid < 512) {
        float s = 0.f;
        #pragma unroll
        for (int k = 0; k < QSEG; ++k) s += red[k][tid];
        wsB[((long long)c * nsb + sb) * 512 + tid] = s;
    }
}

__global__ __launch_bounds__(64) void reduce_kernel(
    const float* __restrict__ wsB,
    float* __restrict__ out,
    int nsb, int n_chunks)
{
    const int b = blockIdx.x;                     // 8 blocks per chunk
    const int c = b >> 3, q = b & 7;
    const int e = q * 64 + threadIdx.x;           // 0..511
    float s = 0.f;
    #pragma unroll 4
    for (int sb = 0; sb < nsb; ++sb)
        s += wsB[((long long)c * nsb + sb) * 512 + e];
    if (e < 384) out[(long long)c * 384 + e] = s;                    // feat
    else out[(long long)n_chunks * 384 + (long long)c * P + (e - 384)] = s;
}

extern "C" void kernel_launch(void* const* d_in, const int* in_sizes, int n_in,
                              void* d_out, int out_size, void* d_ws, size_t ws_size,
                              hipStream_t stream)
{
    const float* density = (const float*)d_in[0];
    const float* feature = (const float*)d_in[1];
    const float* depth   = (const float*)d_in[2];
    float* out = (float*)d_out;

    const int B = in_sizes[0] / P;        // 65536
    const int chunk = 8192;               // matches setup_inputs() chunk_size
    const int n_chunks = B / chunk;       // 8
    const int nsb = chunk / 64;           // 128 superblocks per chunk

    float* wsA  = (float*)d_ws;                              // 3 MB
    float* wsBS = wsA + (size_t)n_chunks * NSBH * QSEG * P;  // 0.2 MB
    float* wsB  = wsBS + (size_t)n_chunks * NSBH * P;        // 2 MB

    dim3 grid1(NSBH, n_chunks);
    seg_sum_kernel<<<grid1, 512, 0, stream>>>(density, depth, wsA, wsBS, chunk);
    dim3 grid2(n_chunks, nsb);            // transposed: live blocks contiguous
    composite_kernel<<<grid2, 1024, 0, stream>>>(density, feature, depth,
                                                 wsA, wsBS, wsB, nsb, chunk);
    reduce_kernel<<<n_chunks * 8, 64, 0, stream>>>(wsB, out, nsb, n_chunks);
}